// Round 1
// 730.380 us; speedup vs baseline: 1.0128x; 1.0128x over previous
//
#include <hip/hip_runtime.h>
#include <math.h>

constexpr int DH  = 256;
constexpr int DZ  = 128;
constexpr float EPS   = 1e-5f;
constexpr float SLOPE = 0.01f;

typedef __attribute__((ext_vector_type(8))) short bf16x8;
typedef __attribute__((ext_vector_type(4))) float f32x4;

__device__ __forceinline__ short f2bf(float f) {
    union { float f; unsigned u; } v; v.f = f;
    unsigned r = v.u + 0x7fffu + ((v.u >> 16) & 1u);   // RNE
    return (short)(r >> 16);
}
__device__ __forceinline__ float bf2f(short s) {
    union { unsigned u; float f; } v;
    v.u = ((unsigned)(unsigned short)s) << 16;
    return v.f;
}

// ---------------------------------------------------------------------------
// degree (int) / dinv
// ---------------------------------------------------------------------------
__global__ void deg_count_i(const int* __restrict__ dst, int* __restrict__ deg, int E) {
    int e = blockIdx.x * blockDim.x + threadIdx.x;
    if (e < E) atomicAdd(&deg[dst[e]], 1);
}

__global__ void make_dinv(const int* __restrict__ deg, float* __restrict__ dinv, int N) {
    int i = blockIdx.x * blockDim.x + threadIdx.x;
    if (i < N) dinv[i] = rsqrtf((float)deg[i] + 1.0f);
}

// ---------------------------------------------------------------------------
// exclusive scan of deg[N] -> rowptr
// ---------------------------------------------------------------------------
__global__ __launch_bounds__(256)
void scan1(const int* __restrict__ deg, int* __restrict__ rowptr,
           int* __restrict__ blocksum, int N) {
    __shared__ int ts[256];
    int base = blockIdx.x * 1024 + threadIdx.x * 4;
    int v[4], s = 0;
#pragma unroll
    for (int i = 0; i < 4; ++i) {
        v[i] = (base + i < N) ? deg[base + i] : 0;
        s += v[i];
    }
    ts[threadIdx.x] = s;
    __syncthreads();
    for (int off = 1; off < 256; off <<= 1) {
        int t = 0;
        if ((int)threadIdx.x >= off) t = ts[threadIdx.x - off];
        __syncthreads();
        if ((int)threadIdx.x >= off) ts[threadIdx.x] += t;
        __syncthreads();
    }
    int run = ts[threadIdx.x] - s;
#pragma unroll
    for (int i = 0; i < 4; ++i) {
        if (base + i < N) rowptr[base + i] = run;
        run += v[i];
    }
    if (threadIdx.x == 255) blocksum[blockIdx.x] = ts[255];
}

__global__ __launch_bounds__(256)
void scan2(const int* __restrict__ blocksum, int* __restrict__ blockoff,
           int nb, int* __restrict__ rowptr_last) {
    __shared__ int ts[256];
    int v = ((int)threadIdx.x < nb) ? blocksum[threadIdx.x] : 0;
    ts[threadIdx.x] = v;
    __syncthreads();
    for (int off = 1; off < 256; off <<= 1) {
        int t = 0;
        if ((int)threadIdx.x >= off) t = ts[threadIdx.x - off];
        __syncthreads();
        if ((int)threadIdx.x >= off) ts[threadIdx.x] += t;
        __syncthreads();
    }
    blockoff[threadIdx.x] = ts[threadIdx.x] - v;
    if (threadIdx.x == 255) *rowptr_last = ts[255];
}

__global__ void scan3(int* __restrict__ rowptr, const int* __restrict__ blockoff, int N) {
    int i = blockIdx.x * blockDim.x + threadIdx.x;
    if (i < N) rowptr[i] += blockoff[i >> 10];
}

// csr_fill now also precomputes the per-edge weight dinv[src]*dinv[dst] and
// stores {src, w} interleaved -> removes the dependent random dinv gather
// from all 4 aggregation dispatches.
__global__ void csr_fill(const int* __restrict__ src, const int* __restrict__ dst,
                         const int* __restrict__ rowptr, int* __restrict__ fill,
                         int2* __restrict__ csr_iw, const float* __restrict__ dinv,
                         int E) {
    int e = blockIdx.x * blockDim.x + threadIdx.x;
    if (e >= E) return;
    int d = dst[e];
    int s = src[e];
    int pos = rowptr[d] + atomicAdd(&fill[d], 1);
    float w = dinv[d] * dinv[s];
    csr_iw[pos] = make_int2(s, __float_as_int(w));
}

// ---------------------------------------------------------------------------
// casts
// ---------------------------------------------------------------------------
__global__ void cast_bf16(const float* __restrict__ x, short* __restrict__ y, int n4) {
    int i = blockIdx.x * blockDim.x + threadIdx.x;
    if (i >= n4) return;
    float4 v = ((const float4*)x)[i];
    short4 o;
    o.x = f2bf(v.x); o.y = f2bf(v.y); o.z = f2bf(v.z); o.w = f2bf(v.w);
    ((short4*)y)[i] = o;
}

__global__ void wt_cast(const float* __restrict__ W, short* __restrict__ Wt, int K, int NC) {
    int idx = blockIdx.x * blockDim.x + threadIdx.x;
    if (idx >= K * NC) return;
    int n = idx / K, k = idx % K;
    Wt[idx] = f2bf(W[k * NC + n]);
}

// ---------------------------------------------------------------------------
// bf16 MFMA GEMM: C[M,NC](bf16) = A[M,K](bf16) @ Wt[NC,K]^T
// Double-buffered: issue next K-tile's global_load_lds before ds_read+MFMA
// of the current tile; ONE barrier per K-step (was two, with a full vmcnt
// drain right after the stage -> zero overlap).
// ---------------------------------------------------------------------------
__global__ __launch_bounds__(256)
void gemm_mfma(const short* __restrict__ A, const short* __restrict__ Bt,
               short* __restrict__ C, int M, int K, int NC) {
    __shared__ short As[2][128 * 32];
    __shared__ short Bs[2][128 * 32];
    const int tid  = threadIdx.x;
    const int lane = tid & 63;
    const int w    = tid >> 6;
    const int wm   = w & 1, wn = w >> 1;
    const int bm   = blockIdx.x * 128;
    const int bn   = blockIdx.y * 128;

    const int srow = w * 16 + (lane >> 2);
    const int scol = (lane & 3) * 8;

    const int ga_r0 = (bm + srow      < M) ? bm + srow      : M - 1;
    const int ga_r1 = (bm + srow + 64 < M) ? bm + srow + 64 : M - 1;
    const size_t arow0 = (size_t)ga_r0 * K;
    const size_t arow1 = (size_t)ga_r1 * K;
    const size_t brow0 = (size_t)(bn + srow) * K;
    const size_t brow1 = (size_t)(bn + srow + 64) * K;

    auto stage = [&](int buf, int k0) {
        __builtin_amdgcn_global_load_lds(
            (const __attribute__((address_space(1))) void*)(A + arow0 + k0 + scol),
            (__attribute__((address_space(3))) void*)&As[buf][srow * 32 + scol], 16, 0, 0);
        __builtin_amdgcn_global_load_lds(
            (const __attribute__((address_space(1))) void*)(A + arow1 + k0 + scol),
            (__attribute__((address_space(3))) void*)&As[buf][(srow + 64) * 32 + scol], 16, 0, 0);
        __builtin_amdgcn_global_load_lds(
            (const __attribute__((address_space(1))) void*)(Bt + brow0 + k0 + scol),
            (__attribute__((address_space(3))) void*)&Bs[buf][srow * 32 + scol], 16, 0, 0);
        __builtin_amdgcn_global_load_lds(
            (const __attribute__((address_space(1))) void*)(Bt + brow1 + k0 + scol),
            (__attribute__((address_space(3))) void*)&Bs[buf][(srow + 64) * 32 + scol], 16, 0, 0);
    };

    f32x4 acc[4][4];
#pragma unroll
    for (int i = 0; i < 4; ++i)
#pragma unroll
        for (int j = 0; j < 4; ++j) acc[i][j] = (f32x4){0.f, 0.f, 0.f, 0.f};

    const int frow = lane & 15;
    const int kg   = (lane >> 4) * 8;
    const int nk   = K >> 5;

    stage(0, 0);
    __syncthreads();   // compiler emits vmcnt(0) drain here: buf0 complete

    for (int kk = 0; kk < nk; ++kk) {
        const int cur = kk & 1;
        if (kk + 1 < nk) stage(cur ^ 1, (kk + 1) << 5);   // in flight across compute

        bf16x8 af[4], bfr[4];
#pragma unroll
        for (int i = 0; i < 4; ++i)
            af[i] = *(const bf16x8*)&As[cur][(wm * 64 + i * 16 + frow) * 32 + kg];
#pragma unroll
        for (int j = 0; j < 4; ++j)
            bfr[j] = *(const bf16x8*)&Bs[cur][(wn * 64 + j * 16 + frow) * 32 + kg];
#pragma unroll
        for (int i = 0; i < 4; ++i)
#pragma unroll
            for (int j = 0; j < 4; ++j)
                acc[i][j] = __builtin_amdgcn_mfma_f32_16x16x32_bf16(
                    af[i], bfr[j], acc[i][j], 0, 0, 0);

        __syncthreads();   // drains vmcnt (next buf ready) + lgkm (reads done)
    }

    const int row_base = bm + wm * 64 + (lane >> 4) * 4;
    const int col_base = bn + wn * 64 + (lane & 15);
#pragma unroll
    for (int i = 0; i < 4; ++i) {
#pragma unroll
        for (int r = 0; r < 4; ++r) {
            int row = row_base + i * 16 + r;
            if (row < M) {
                short* cp = C + (size_t)row * NC + col_base;
#pragma unroll
                for (int j = 0; j < 4; ++j) cp[j * 16] = f2bf(acc[i][j][r]);
            }
        }
    }
}

// ---------------------------------------------------------------------------
// CSR aggregation (bf16 gather, fp32 acc) + fused LN partial stats.
// D=256: 32 lanes/node (16B=short8 per lane), 2 nodes/wave.
// Edge stream is {src, w} int2 pairs: one sequential 8B load per edge,
// no dependent dinv gather in the chain.
// ---------------------------------------------------------------------------
__global__ __launch_bounds__(256)
void agg_ln_csr(const short* __restrict__ h, const int* __restrict__ rowptr,
                const int2* __restrict__ csr_iw, const float* __restrict__ dinv,
                const float* __restrict__ bias, short* __restrict__ agg,
                float* __restrict__ psum, float* __restrict__ psumsq, int N) {
    constexpr int TPN = 32;                 // D=256 bf16 -> 32 x 16B
    int t = blockIdx.x * 256 + threadIdx.x;
    int n = t / TPN, l = t % TPN;
    float acc[8] = {0.f, 0.f, 0.f, 0.f, 0.f, 0.f, 0.f, 0.f};
    if (n < N) {
        const bf16x8* h8 = (const bf16x8*)h;   // row = 32 vectors
        float di = dinv[n];
        float sl2 = di * di;
        bf16x8 sv = h8[(size_t)n * TPN + l];
        const float* bp = bias + l * 8;
#pragma unroll
        for (int c = 0; c < 8; ++c) acc[c] = bf2f(sv[c]) * sl2 + bp[c];
        int j = rowptr[n], j1 = rowptr[n + 1];
        for (; j + 3 < j1; j += 4) {
            int2 e0 = csr_iw[j],     e1 = csr_iw[j + 1];
            int2 e2 = csr_iw[j + 2], e3 = csr_iw[j + 3];
            float w0 = __int_as_float(e0.y), w1 = __int_as_float(e1.y);
            float w2 = __int_as_float(e2.y), w3 = __int_as_float(e3.y);
            bf16x8 v0 = h8[(size_t)e0.x * TPN + l];
            bf16x8 v1 = h8[(size_t)e1.x * TPN + l];
            bf16x8 v2 = h8[(size_t)e2.x * TPN + l];
            bf16x8 v3 = h8[(size_t)e3.x * TPN + l];
#pragma unroll
            for (int c = 0; c < 8; ++c)
                acc[c] += bf2f(v0[c]) * w0 + bf2f(v1[c]) * w1 +
                          bf2f(v2[c]) * w2 + bf2f(v3[c]) * w3;
        }
        if (j + 1 < j1) {
            int2 e0 = csr_iw[j], e1 = csr_iw[j + 1];
            float w0 = __int_as_float(e0.y), w1 = __int_as_float(e1.y);
            bf16x8 v0 = h8[(size_t)e0.x * TPN + l];
            bf16x8 v1 = h8[(size_t)e1.x * TPN + l];
#pragma unroll
            for (int c = 0; c < 8; ++c)
                acc[c] += bf2f(v0[c]) * w0 + bf2f(v1[c]) * w1;
            j += 2;
        }
        if (j < j1) {
            int2 e0 = csr_iw[j];
            float w0 = __int_as_float(e0.y);
            bf16x8 v0 = h8[(size_t)e0.x * TPN + l];
#pragma unroll
            for (int c = 0; c < 8; ++c) acc[c] += bf2f(v0[c]) * w0;
        }
        bf16x8 o;
#pragma unroll
        for (int c = 0; c < 8; ++c) o[c] = f2bf(acc[c]);
        ((bf16x8*)agg)[(size_t)n * TPN + l] = o;
    }
    // LN partial stats
    float s = 0.f, q = 0.f;
#pragma unroll
    for (int c = 0; c < 8; ++c) { s += acc[c]; q += acc[c] * acc[c]; }
#pragma unroll
    for (int off = 32; off; off >>= 1) {
        s += __shfl_down(s, off);
        q += __shfl_down(q, off);
    }
    __shared__ float ss[4], qq[4];
    int wid = threadIdx.x >> 6, lane = threadIdx.x & 63;
    if (lane == 0) { ss[wid] = s; qq[wid] = q; }
    __syncthreads();
    if (threadIdx.x == 0) {
        psum[blockIdx.x]   = ss[0] + ss[1] + ss[2] + ss[3];
        psumsq[blockIdx.x] = qq[0] + qq[1] + qq[2] + qq[3];
    }
}

// final layer: D=128, 16 lanes/node (16B), 4 nodes/wave, fp32 out, no stats
__global__ __launch_bounds__(256)
void agg_out_csr(const short* __restrict__ h, const int* __restrict__ rowptr,
                 const int2* __restrict__ csr_iw, const float* __restrict__ dinv,
                 const float* __restrict__ bias, float* __restrict__ out, int N) {
    constexpr int TPN = 16;                 // D=128 bf16 -> 16 x 16B
    int t = blockIdx.x * 256 + threadIdx.x;
    int n = t / TPN, l = t % TPN;
    if (n >= N) return;
    const bf16x8* h8 = (const bf16x8*)h;
    float di = dinv[n];
    float sl2 = di * di;
    bf16x8 sv = h8[(size_t)n * TPN + l];
    const float* bp = bias + l * 8;
    float acc[8];
#pragma unroll
    for (int c = 0; c < 8; ++c) acc[c] = bf2f(sv[c]) * sl2 + bp[c];
    int j = rowptr[n], j1 = rowptr[n + 1];
    for (; j + 3 < j1; j += 4) {
        int2 e0 = csr_iw[j],     e1 = csr_iw[j + 1];
        int2 e2 = csr_iw[j + 2], e3 = csr_iw[j + 3];
        float w0 = __int_as_float(e0.y), w1 = __int_as_float(e1.y);
        float w2 = __int_as_float(e2.y), w3 = __int_as_float(e3.y);
        bf16x8 v0 = h8[(size_t)e0.x * TPN + l];
        bf16x8 v1 = h8[(size_t)e1.x * TPN + l];
        bf16x8 v2 = h8[(size_t)e2.x * TPN + l];
        bf16x8 v3 = h8[(size_t)e3.x * TPN + l];
#pragma unroll
        for (int c = 0; c < 8; ++c)
            acc[c] += bf2f(v0[c]) * w0 + bf2f(v1[c]) * w1 +
                      bf2f(v2[c]) * w2 + bf2f(v3[c]) * w3;
    }
    if (j + 1 < j1) {
        int2 e0 = csr_iw[j], e1 = csr_iw[j + 1];
        float w0 = __int_as_float(e0.y), w1 = __int_as_float(e1.y);
        bf16x8 v0 = h8[(size_t)e0.x * TPN + l];
        bf16x8 v1 = h8[(size_t)e1.x * TPN + l];
#pragma unroll
        for (int c = 0; c < 8; ++c)
            acc[c] += bf2f(v0[c]) * w0 + bf2f(v1[c]) * w1;
        j += 2;
    }
    if (j < j1) {
        int2 e0 = csr_iw[j];
        float w0 = __int_as_float(e0.y);
        bf16x8 v0 = h8[(size_t)e0.x * TPN + l];
#pragma unroll
        for (int c = 0; c < 8; ++c) acc[c] += bf2f(v0[c]) * w0;
    }
    float4* op = (float4*)(out + (size_t)n * 128 + l * 8);
    op[0] = make_float4(acc[0], acc[1], acc[2], acc[3]);
    op[1] = make_float4(acc[4], acc[5], acc[6], acc[7]);
}

// ---------------------------------------------------------------------------
// LN finalize: reduce per-block partials -> (mean, 1/(std+eps))
// ---------------------------------------------------------------------------
__global__ __launch_bounds__(1024)
void ln_finalize2(const float* __restrict__ psum, const float* __restrict__ psumsq,
                  int nb, float* __restrict__ scl, double M) {
    double s = 0.0, q = 0.0;
    for (int i = threadIdx.x; i < nb; i += 1024) {
        s += (double)psum[i];
        q += (double)psumsq[i];
    }
#pragma unroll
    for (int off = 32; off; off >>= 1) {
        s += __shfl_down(s, off);
        q += __shfl_down(q, off);
    }
    __shared__ double ss[16], qq[16];
    int wid = threadIdx.x >> 6, lane = threadIdx.x & 63;
    if (lane == 0) { ss[wid] = s; qq[wid] = q; }
    __syncthreads();
    if (threadIdx.x == 0) {
        double S = 0.0, Q = 0.0;
        for (int i = 0; i < 16; ++i) { S += ss[i]; Q += qq[i]; }
        double mu  = S / M;
        double var = Q / M - mu * mu;
        if (var < 0.0) var = 0.0;
        float sd = (float)sqrt(var);
        scl[0] = (float)mu;
        scl[1] = 1.0f / (sd + EPS);
    }
}

// ---------------------------------------------------------------------------
// LN apply + leaky_relu: bf16 in -> bf16 out
// ---------------------------------------------------------------------------
__global__ void ln_apply_bf(const short* __restrict__ x, const float* __restrict__ gamma,
                            const float* __restrict__ beta, const float* __restrict__ scl,
                            short* __restrict__ y, int total4, int D4) {
    int idx = blockIdx.x * blockDim.x + threadIdx.x;
    if (idx >= total4) return;
    float mean = scl[0], inv = scl[1];
    int c4 = (idx % D4) * 4;
    short4 v = ((const short4*)x)[idx];
    float4 g = *(const float4*)(gamma + c4);
    float4 b = *(const float4*)(beta + c4);
    float o0 = (bf2f(v.x) - mean) * inv * g.x + b.x;
    float o1 = (bf2f(v.y) - mean) * inv * g.y + b.y;
    float o2 = (bf2f(v.z) - mean) * inv * g.z + b.z;
    float o3 = (bf2f(v.w) - mean) * inv * g.w + b.w;
    o0 = o0 > 0.f ? o0 : SLOPE * o0;
    o1 = o1 > 0.f ? o1 : SLOPE * o1;
    o2 = o2 > 0.f ? o2 : SLOPE * o2;
    o3 = o3 > 0.f ? o3 : SLOPE * o3;
    short4 o;
    o.x = f2bf(o0); o.y = f2bf(o1); o.z = f2bf(o2); o.w = f2bf(o3);
    ((short4*)y)[idx] = o;
}

// ---------------------------------------------------------------------------
// launcher
// ---------------------------------------------------------------------------
extern "C" void kernel_launch(void* const* d_in, const int* in_sizes, int n_in,
                              void* d_out, int out_size, void* d_ws, size_t ws_size,
                              hipStream_t stream) {
    const float* x   = (const float*)d_in[0];
    const int*   ei  = (const int*)d_in[1];
    const float* W1  = (const float*)d_in[2];
    const float* b1  = (const float*)d_in[3];
    const float* g1  = (const float*)d_in[4];
    const float* be1 = (const float*)d_in[5];
    const float* W2  = (const float*)d_in[6];
    const float* b2  = (const float*)d_in[7];
    const float* g2  = (const float*)d_in[8];
    const float* be2 = (const float*)d_in[9];
    const float* W3  = (const float*)d_in[10];
    const float* b3  = (const float*)d_in[11];
    const float* g3  = (const float*)d_in[12];
    const float* be3 = (const float*)d_in[13];
    const float* W4  = (const float*)d_in[14];
    const float* b4  = (const float*)d_in[15];

    const int N = in_sizes[0] / DH;   // 100000
    const int E = in_sizes[1] / 2;    // 800000
    const int* src = ei;
    const int* dst = ei + E;
    const int nb = (N + 1023) / 1024;
    const int nagg = (N * 32 + 255) / 256;   // agg_ln_csr blocks (12500)

    char* w = (char*)d_ws;
    size_t off = 0;
    auto alloc = [&](size_t bytes) { char* p = w + off; off = (off + bytes + 255) & ~(size_t)255; return p; };
    int*    deg      = (int*)alloc((size_t)N * 4);
    int*    rowptr   = (int*)alloc((size_t)(N + 1) * 4);
    int*    blocksum = (int*)alloc(256 * 4);
    int*    blockoff = (int*)alloc(256 * 4);
    float*  dinv     = (float*)alloc((size_t)N * 4);
    float*  scl      = (float*)alloc(64);
    float*  psum     = (float*)alloc((size_t)nagg * 4);
    float*  psumsq   = (float*)alloc((size_t)nagg * 4);
    int2*   csr_iw   = (int2*)alloc((size_t)E * 8);
    short*  Wt1      = (short*)alloc((size_t)DH * DH * 2);
    short*  Wt2      = (short*)alloc((size_t)DH * DH * 2);
    short*  Wt3      = (short*)alloc((size_t)DH * DH * 2);
    short*  Wt4      = (short*)alloc((size_t)DZ * DH * 2);
    short*  actbf    = (short*)alloc((size_t)N * DH * 2);
    short*  hbf      = (short*)alloc((size_t)N * DH * 2);
    short*  aggb     = (short*)alloc((size_t)N * DH * 2);

    // ---- degree, dinv, CSR build ----
    hipMemsetAsync(deg, 0, (size_t)N * 4, stream);
    deg_count_i<<<(E + 255) / 256, 256, 0, stream>>>(dst, deg, E);
    make_dinv<<<(N + 255) / 256, 256, 0, stream>>>(deg, dinv, N);
    scan1<<<nb, 256, 0, stream>>>(deg, rowptr, blocksum, N);
    scan2<<<1, 256, 0, stream>>>(blocksum, blockoff, nb, rowptr + N);
    scan3<<<(N + 255) / 256, 256, 0, stream>>>(rowptr, blockoff, N);
    hipMemsetAsync(deg, 0, (size_t)N * 4, stream);
    csr_fill<<<(E + 255) / 256, 256, 0, stream>>>(src, dst, rowptr, deg, csr_iw, dinv, E);

    // ---- weight transpose+cast, input cast ----
    wt_cast<<<(DH * DH + 255) / 256, 256, 0, stream>>>(W1, Wt1, DH, DH);
    wt_cast<<<(DH * DH + 255) / 256, 256, 0, stream>>>(W2, Wt2, DH, DH);
    wt_cast<<<(DH * DH + 255) / 256, 256, 0, stream>>>(W3, Wt3, DH, DH);
    wt_cast<<<(DH * DZ + 255) / 256, 256, 0, stream>>>(W4, Wt4, DH, DZ);
    cast_bf16<<<(N * DH / 4 + 255) / 256, 256, 0, stream>>>(x, actbf, N * DH / 4);

    const int gmM = (N + 127) / 128;
    auto layer = [&](const short* Wt, const float* b, const float* g, const float* be) {
        gemm_mfma<<<dim3(gmM, DH / 128), 256, 0, stream>>>(actbf, Wt, hbf, N, DH, DH);
        agg_ln_csr<<<nagg, 256, 0, stream>>>(hbf, rowptr, csr_iw, dinv, b, aggb,
                                             psum, psumsq, N);
        ln_finalize2<<<1, 1024, 0, stream>>>(psum, psumsq, nagg, scl, (double)N * DH);
        int t4 = N * (DH / 4);
        ln_apply_bf<<<(t4 + 255) / 256, 256, 0, stream>>>(aggb, g, be, scl, actbf,
                                                          t4, DH / 4);
    };

    layer(Wt1, b1, g1, be1);
    layer(Wt2, b2, g2, be2);
    layer(Wt3, b3, g3, be3);

    // final conv: DH -> DZ
    gemm_mfma<<<dim3(gmM, DZ / 128), 256, 0, stream>>>(actbf, Wt4, hbf, N, DH, DZ);
    float* out = (float*)d_out;
    int naggz = (N * 16 + 255) / 256;
    agg_out_csr<<<naggz, 256, 0, stream>>>(hbf, rowptr, csr_iw, dinv, b4, out, N);
}